// Round 1
// baseline (356.008 us; speedup 1.0000x reference)
//
#include <hip/hip_runtime.h>
#include <math.h>

#define D 256
#define T 4096

typedef __attribute__((ext_vector_type(8))) short bf16x8;
typedef __attribute__((ext_vector_type(4))) float f32x4;

__device__ __forceinline__ unsigned short f2bf(float x){
  unsigned int u = __float_as_uint(x);
  unsigned int r = (u + 0x7FFFu + ((u >> 16) & 1u)) >> 16;
  return (unsigned short)r;
}

__device__ __forceinline__ void gl_lds16(const void* g, void* l){
  __builtin_amdgcn_global_load_lds((const __attribute__((address_space(1))) unsigned int*)g,
                                   (__attribute__((address_space(3))) unsigned int*)l, 16, 0, 0);
}

// ---------------- prep0: gate vectors ----------------
__global__ __launch_bounds__(256) void prep0_kernel(
    const float* __restrict__ q_vec, const float* __restrict__ k_vec,
    const float* __restrict__ v_vec, const float* __restrict__ Ws,
    const float* __restrict__ bs, const float* __restrict__ Wt,
    const float* __restrict__ bt, float* __restrict__ gates){
  __shared__ float vv[D];
  int t = threadIdx.x;
  vv[t]         = 1.f/(1.f + __expf(-v_vec[t]));
  gates[t]      = 1.f/(1.f + __expf(-q_vec[t]));   // gq
  gates[D + t]  = 1.f/(1.f + __expf(-k_vec[t]));   // gk
  __syncthreads();
  float s1 = bs[t], s2 = bt[t];
  for(int d0=0; d0<D; d0++){ s1 += Ws[t*D+d0]*vv[d0]; s2 += Wt[t*D+d0]*vv[d0]; }
  gates[2*D + t] = (1.f/(1.f + __expf(-s1))) * tanhf(s2);  // v_gate
}

// ---------------- proj: q = (query @ Wq^T + bq) * gq,  bf16 out ----------------
__global__ __launch_bounds__(256) void proj_kernel(
    const float* __restrict__ query, const float* __restrict__ Wq,
    const float* __restrict__ bq, const float* __restrict__ gates,
    unsigned short* __restrict__ q_g){
  __shared__ __align__(16) unsigned short wbuf[D*40];  // [256 e][40] (80B rows, 32 real d + pad)
  int tid = threadIdx.x; int w = tid >> 6; int l = tid & 63;
  int lr = l & 15, lc = l >> 4;
  int r0 = blockIdx.x * 64;
  f32x4 acc[16];
  #pragma unroll
  for(int n=0;n<16;n++) acc[n] = (f32x4){0.f,0.f,0.f,0.f};
  const float* qrow = query + (size_t)(r0 + w*16 + lr)*D;
  for(int kc=0; kc<8; kc++){
    __syncthreads();
    #pragma unroll
    for(int i=0;i<4;i++){
      int g = i*256 + tid; int e = g >> 2, u = g & 3;
      const float* src = Wq + (size_t)e*D + kc*32 + u*8;
      bf16x8 pk;
      #pragma unroll
      for(int x=0;x<8;x++) pk[x] = (short)f2bf(src[x]);
      *(bf16x8*)&wbuf[e*40 + u*8] = pk;
    }
    __syncthreads();
    bf16x8 af;
    {
      const float* s = qrow + kc*32 + lc*8;
      #pragma unroll
      for(int x=0;x<8;x++) af[x] = (short)f2bf(s[x]);
    }
    #pragma unroll
    for(int n=0;n<16;n++){
      bf16x8 bfrag = *(const bf16x8*)&wbuf[(n*16 + lr)*40 + lc*8];
      acc[n] = __builtin_amdgcn_mfma_f32_16x16x32_bf16(af, bfrag, acc[n], 0, 0, 0);
    }
  }
  #pragma unroll
  for(int n=0;n<16;n++){
    int col = n*16 + lr;
    float bb = bq[col], gg = gates[col];
    #pragma unroll
    for(int r=0;r<4;r++){
      int row = r0 + w*16 + lc*4 + r;
      q_g[(size_t)row*D + col] = f2bf((acc[n][r] + bb) * gg);
    }
  }
}

// ---------------- prep1: K (row-padded) and V^T (transposed, padded) bf16 tiles ----------------
// k_g:  per (b,jt) tile: 32 rows x 528B (264 ushort), tile stride 17408B
// vt_g: per (b,jt) tile: 256 d-rows x 80B (40 ushort), tile stride 20480B
__global__ __launch_bounds__(256) void prep1_kernel(
    const float* __restrict__ value, const float* __restrict__ gates,
    unsigned short* __restrict__ k_g, unsigned short* __restrict__ vt_g){
  int tid = threadIdx.x;
  int b = blockIdx.x >> 7, jt = blockIdx.x & 127;
  const float* vbase = value + ((size_t)b*T + jt*32)*D;
  const float* gk = gates + D;
  const float* vg = gates + 2*D;
  unsigned short* kt = k_g  + (size_t)blockIdx.x * (17408/2);
  unsigned short* vt = vt_g + (size_t)blockIdx.x * (20480/2);
  #pragma unroll
  for(int i=0;i<4;i++){
    int g = i*256 + tid; int j = g >> 5, c = g & 31;
    const float* src = vbase + j*D + c*8;
    bf16x8 pk;
    #pragma unroll
    for(int x=0;x<8;x++) pk[x] = (short)f2bf(src[x] * gk[c*8+x]);
    *(bf16x8*)&kt[j*264 + c*8] = pk;
  }
  #pragma unroll
  for(int i=0;i<4;i++){
    int g = i*256 + tid; int d0 = g >> 2, u = g & 3;
    float gd = vg[d0];
    bf16x8 pk;
    #pragma unroll
    for(int x=0;x<8;x++) pk[x] = (short)f2bf(vbase[(u*8+x)*D + d0] * gd);
    *(bf16x8*)&vt[d0*40 + u*8] = pk;
  }
}

// ---------------- flash attention ----------------
__global__ __launch_bounds__(256) void flash_kernel(
    const unsigned short* __restrict__ q_g,
    const unsigned short* __restrict__ k_g,
    const unsigned short* __restrict__ vt_g,
    float* __restrict__ out){
  __shared__ __align__(16) unsigned short kbuf[17408/2];   // [32][264]
  __shared__ __align__(16) unsigned short vtbuf[20480/2];  // [256][40]
  __shared__ __align__(16) unsigned short pbuf[4][16][40]; // per-wave P, padded rows
  int tid = threadIdx.x; int w = tid >> 6, l = tid & 63;
  int lr = l & 15, lc = l >> 4;
  int b = blockIdx.x >> 6, rblk = blockIdx.x & 63;
  int r0 = rblk * 64;
  int wrow0 = r0 + w*16;

  bf16x8 qf[8];
  {
    const unsigned short* qbase = q_g + ((size_t)b*T + wrow0 + lr)*D + lc*8;
    #pragma unroll
    for(int kc=0;kc<8;kc++) qf[kc] = *(const bf16x8*)(qbase + kc*32);
  }
  f32x4 o[16];
  #pragma unroll
  for(int n=0;n<16;n++) o[n] = (f32x4){0.f,0.f,0.f,0.f};
  float m[4]    = {-INFINITY,-INFINITY,-INFINITY,-INFINITY};
  float lsum[4] = {0.f,0.f,0.f,0.f};
  int ntiles = r0/32 + 2;
  int rmax = wrow0 + 15;

  for(int jt=0; jt<ntiles; jt++){
    int j0 = jt*32;
    const unsigned short* ksrc = k_g  + (size_t)(b*128 + jt)*(17408/2);
    const unsigned short* vsrc = vt_g + (size_t)(b*128 + jt)*(20480/2);
    for(int c=w; c<17; c+=4) gl_lds16(ksrc + c*512 + l*8, (char*)kbuf  + c*1024);
    for(int c=w; c<20; c+=4) gl_lds16(vsrc + c*512 + l*8, (char*)vtbuf + c*1024);
    __syncthreads();
    bool active = (j0 <= rmax);
    if(active){
      f32x4 s0 = {0,0,0,0}, s1 = {0,0,0,0};
      #pragma unroll
      for(int kc=0;kc<8;kc++){
        bf16x8 k0 = *(const bf16x8*)&kbuf[lr*264        + (kc*4 + lc)*8];
        bf16x8 k1 = *(const bf16x8*)&kbuf[(16 + lr)*264 + (kc*4 + lc)*8];
        s0 = __builtin_amdgcn_mfma_f32_16x16x32_bf16(qf[kc], k0, s0, 0,0,0);
        s1 = __builtin_amdgcn_mfma_f32_16x16x32_bf16(qf[kc], k1, s1, 0,0,0);
      }
      float sv0[4], sv1[4], alpha[4];
      #pragma unroll
      for(int r=0;r<4;r++){
        int gr = wrow0 + lc*4 + r;
        float x0 = s0[r]*0.0625f; int gj0 = j0 + lr;
        float x1 = s1[r]*0.0625f; int gj1 = j0 + 16 + lr;
        if(gj0 > gr || x0 == 0.0f) x0 = -INFINITY;
        if(gj1 > gr || x1 == 0.0f) x1 = -INFINITY;
        sv0[r]=x0; sv1[r]=x1;
      }
      #pragma unroll
      for(int r=0;r<4;r++){
        float mx = fmaxf(sv0[r], sv1[r]);
        #pragma unroll
        for(int dd=1; dd<16; dd<<=1) mx = fmaxf(mx, __shfl_xor(mx, dd));
        float mn = fmaxf(m[r], mx);
        alpha[r] = (m[r] == mn) ? 1.0f : __expf(m[r] - mn);
        float p0 = (sv0[r] == -INFINITY) ? 0.f : __expf(sv0[r] - mn);
        float p1 = (sv1[r] == -INFINITY) ? 0.f : __expf(sv1[r] - mn);
        pbuf[w][lc*4+r][lr]      = f2bf(p0);
        pbuf[w][lc*4+r][16 + lr] = f2bf(p1);
        float ps = p0 + p1;
        #pragma unroll
        for(int dd=1; dd<16; dd<<=1) ps += __shfl_xor(ps, dd);
        lsum[r] = lsum[r]*alpha[r] + ps;
        m[r] = mn;
      }
      #pragma unroll
      for(int n=0;n<16;n++){
        #pragma unroll
        for(int r=0;r<4;r++) o[n][r] *= alpha[r];
      }
    }
    __syncthreads();
    if(active){
      bf16x8 pa = *(const bf16x8*)&pbuf[w][lr][lc*8];
      #pragma unroll
      for(int n=0;n<16;n++){
        bf16x8 vf = *(const bf16x8*)&vtbuf[(n*16 + lr)*40 + lc*8];
        o[n] = __builtin_amdgcn_mfma_f32_16x16x32_bf16(pa, vf, o[n], 0,0,0);
      }
    }
    __syncthreads();
  }

  float* obase = out + ((size_t)b*T + wrow0)*D;
  #pragma unroll
  for(int r=0;r<4;r++){
    float inv = 1.0f / lsum[r];
    #pragma unroll
    for(int n=0;n<16;n++){
      obase[(size_t)(lc*4 + r)*D + n*16 + lr] = o[n][r]*inv;
    }
  }
}

extern "C" void kernel_launch(void* const* d_in, const int* in_sizes, int n_in,
                              void* d_out, int out_size, void* d_ws, size_t ws_size,
                              hipStream_t stream){
  (void)in_sizes; (void)n_in; (void)out_size; (void)ws_size;
  const float* query = (const float*)d_in[0];
  const float* value = (const float*)d_in[1];
  const float* q_vec = (const float*)d_in[2];
  const float* k_vec = (const float*)d_in[3];
  const float* v_vec = (const float*)d_in[4];
  const float* Wq    = (const float*)d_in[5];
  const float* bq    = (const float*)d_in[6];
  const float* Ws    = (const float*)d_in[7];
  const float* bs    = (const float*)d_in[8];
  const float* Wt    = (const float*)d_in[9];
  const float* bt    = (const float*)d_in[10];
  char* ws = (char*)d_ws;
  unsigned short* q_g  = (unsigned short*)(ws);             //  8,388,608 B
  unsigned short* k_g  = (unsigned short*)(ws + 8388608);   //  8,912,896 B
  unsigned short* vt_g = (unsigned short*)(ws + 17301504);  // 10,485,760 B
  float* gates         = (float*)(ws + 27787264);           //  3,072 B
  float* out = (float*)d_out;

  hipLaunchKernelGGL(prep0_kernel, dim3(1),   dim3(256), 0, stream,
                     q_vec, k_vec, v_vec, Ws, bs, Wt, bt, gates);
  hipLaunchKernelGGL(proj_kernel,  dim3(256), dim3(256), 0, stream,
                     query, Wq, bq, gates, q_g);
  hipLaunchKernelGGL(prep1_kernel, dim3(512), dim3(256), 0, stream,
                     value, gates, k_g, vt_g);
  hipLaunchKernelGGL(flash_kernel, dim3(256), dim3(256), 0, stream,
                     q_g, k_g, vt_g, out);
}

// Round 2
// 222.137 us; speedup vs baseline: 1.6027x; 1.6027x over previous
//
#include <hip/hip_runtime.h>
#include <math.h>

#define D 256
#define T 4096

typedef __attribute__((ext_vector_type(8))) short bf16x8;
typedef __attribute__((ext_vector_type(4))) float f32x4;

__device__ __forceinline__ unsigned short f2bf(float x){
  unsigned int u = __float_as_uint(x);
  unsigned int r = (u + 0x7FFFu + ((u >> 16) & 1u)) >> 16;
  return (unsigned short)r;
}

__device__ __forceinline__ void gl_lds16(const void* g, void* l){
  __builtin_amdgcn_global_load_lds((const __attribute__((address_space(1))) unsigned int*)g,
                                   (__attribute__((address_space(3))) unsigned int*)l, 16, 0, 0);
}

// ---------------- prep0: gate vectors ----------------
__global__ __launch_bounds__(256) void prep0_kernel(
    const float* __restrict__ q_vec, const float* __restrict__ k_vec,
    const float* __restrict__ v_vec, const float* __restrict__ Ws,
    const float* __restrict__ bs, const float* __restrict__ Wt,
    const float* __restrict__ bt, float* __restrict__ gates){
  __shared__ float vv[D];
  int t = threadIdx.x;
  vv[t]         = 1.f/(1.f + __expf(-v_vec[t]));
  gates[t]      = 1.f/(1.f + __expf(-q_vec[t]));   // gq
  gates[D + t]  = 1.f/(1.f + __expf(-k_vec[t]));   // gk
  __syncthreads();
  float s1 = bs[t], s2 = bt[t];
  for(int d0=0; d0<D; d0++){ s1 += Ws[t*D+d0]*vv[d0]; s2 += Wt[t*D+d0]*vv[d0]; }
  gates[2*D + t] = (1.f/(1.f + __expf(-s1))) * tanhf(s2);  // v_gate
}

// ---------------- proj: q = (query @ Wq^T + bq) * gq,  bf16 out ----------------
__global__ __launch_bounds__(256) void proj_kernel(
    const float* __restrict__ query, const float* __restrict__ Wq,
    const float* __restrict__ bq, const float* __restrict__ gates,
    unsigned short* __restrict__ q_g){
  __shared__ __align__(16) unsigned short wbuf[D*40];  // [256 e][40] (80B rows, 32 real d + pad)
  int tid = threadIdx.x; int w = tid >> 6; int l = tid & 63;
  int lr = l & 15, lc = l >> 4;
  int r0 = blockIdx.x * 64;
  f32x4 acc[16];
  #pragma unroll
  for(int n=0;n<16;n++) acc[n] = (f32x4){0.f,0.f,0.f,0.f};
  const float* qrow = query + (size_t)(r0 + w*16 + lr)*D;
  for(int kc=0; kc<8; kc++){
    __syncthreads();
    #pragma unroll
    for(int i=0;i<4;i++){
      int g = i*256 + tid; int e = g >> 2, u = g & 3;
      const float* src = Wq + (size_t)e*D + kc*32 + u*8;
      bf16x8 pk;
      #pragma unroll
      for(int x=0;x<8;x++) pk[x] = (short)f2bf(src[x]);
      *(bf16x8*)&wbuf[e*40 + u*8] = pk;
    }
    __syncthreads();
    bf16x8 af;
    {
      const float* s = qrow + kc*32 + lc*8;
      #pragma unroll
      for(int x=0;x<8;x++) af[x] = (short)f2bf(s[x]);
    }
    #pragma unroll
    for(int n=0;n<16;n++){
      bf16x8 bfrag = *(const bf16x8*)&wbuf[(n*16 + lr)*40 + lc*8];
      acc[n] = __builtin_amdgcn_mfma_f32_16x16x32_bf16(af, bfrag, acc[n], 0, 0, 0);
    }
  }
  #pragma unroll
  for(int n=0;n<16;n++){
    int col = n*16 + lr;
    float bb = bq[col], gg = gates[col];
    #pragma unroll
    for(int r=0;r<4;r++){
      int row = r0 + w*16 + lc*4 + r;
      q_g[(size_t)row*D + col] = f2bf((acc[n][r] + bb) * gg);
    }
  }
}

// ---------------- prep1: K (row-padded) and V^T (transposed, padded) bf16 tiles ----------------
__global__ __launch_bounds__(256) void prep1_kernel(
    const float* __restrict__ value, const float* __restrict__ gates,
    unsigned short* __restrict__ k_g, unsigned short* __restrict__ vt_g){
  int tid = threadIdx.x;
  int b = blockIdx.x >> 7, jt = blockIdx.x & 127;
  const float* vbase = value + ((size_t)b*T + jt*32)*D;
  const float* gk = gates + D;
  const float* vg = gates + 2*D;
  unsigned short* kt = k_g  + (size_t)blockIdx.x * (17408/2);
  unsigned short* vt = vt_g + (size_t)blockIdx.x * (20480/2);
  #pragma unroll
  for(int i=0;i<4;i++){
    int g = i*256 + tid; int j = g >> 5, c = g & 31;
    const float* src = vbase + j*D + c*8;
    bf16x8 pk;
    #pragma unroll
    for(int x=0;x<8;x++) pk[x] = (short)f2bf(src[x] * gk[c*8+x]);
    *(bf16x8*)&kt[j*264 + c*8] = pk;
  }
  #pragma unroll
  for(int i=0;i<4;i++){
    int g = i*256 + tid; int d0 = g >> 2, u = g & 3;
    float gd = vg[d0];
    bf16x8 pk;
    #pragma unroll
    for(int x=0;x<8;x++) pk[x] = (short)f2bf(vbase[(u*8+x)*D + d0] * gd);
    *(bf16x8*)&vt[d0*40 + u*8] = pk;
  }
}

// ---------------- flash attention, 2-way KV split ----------------
// split 0 -> out0 (d_out, f32 unnormalized), split 1 -> out1 (ws, f32)
// ml[s][b*T+row][2] = {m, l}
__global__ __launch_bounds__(256) void flash_kernel(
    const unsigned short* __restrict__ q_g,
    const unsigned short* __restrict__ k_g,
    const unsigned short* __restrict__ vt_g,
    float* __restrict__ out0, float* __restrict__ out1,
    float* __restrict__ ml){
  __shared__ __align__(16) unsigned short kbuf[17408/2];   // [32][264]
  __shared__ __align__(16) unsigned short vtbuf[20480/2];  // [256][40]
  __shared__ __align__(16) unsigned short pbuf[4][16][40]; // per-wave P, padded rows
  int tid = threadIdx.x; int w = tid >> 6, l = tid & 63;
  int lr = l & 15, lc = l >> 4;
  int bid = blockIdx.x;
  int rblk = 63 - (bid >> 3);        // heavy blocks first (LPT)
  int b = (bid >> 1) & 3;
  int s = bid & 1;
  int r0 = rblk * 64;
  int wrow0 = r0 + w*16;

  bf16x8 qf[8];
  {
    const unsigned short* qbase = q_g + ((size_t)b*T + wrow0 + lr)*D + lc*8;
    #pragma unroll
    for(int kc=0;kc<8;kc++) qf[kc] = *(const bf16x8*)(qbase + kc*32);
  }
  f32x4 o[16];
  #pragma unroll
  for(int n=0;n<16;n++) o[n] = (f32x4){0.f,0.f,0.f,0.f};
  float m[4]    = {-INFINITY,-INFINITY,-INFINITY,-INFINITY};
  float lsum[4] = {0.f,0.f,0.f,0.f};
  int nt = r0/32 + 2;
  int h  = (nt + 1) >> 1;
  int jt0 = s ? h  : 0;
  int jt1 = s ? nt : h;
  int rmax = wrow0 + 15;

  for(int jt=jt0; jt<jt1; jt++){
    int j0 = jt*32;
    const unsigned short* ksrc = k_g  + (size_t)(b*128 + jt)*(17408/2);
    const unsigned short* vsrc = vt_g + (size_t)(b*128 + jt)*(20480/2);
    for(int c=w; c<17; c+=4) gl_lds16(ksrc + c*512 + l*8, (char*)kbuf  + c*1024);
    for(int c=w; c<20; c+=4) gl_lds16(vsrc + c*512 + l*8, (char*)vtbuf + c*1024);
    __syncthreads();
    bool active = (j0 <= rmax);
    if(active){
      f32x4 s0 = {0,0,0,0}, s1 = {0,0,0,0};
      #pragma unroll
      for(int kc=0;kc<8;kc++){
        bf16x8 k0 = *(const bf16x8*)&kbuf[lr*264        + (kc*4 + lc)*8];
        bf16x8 k1 = *(const bf16x8*)&kbuf[(16 + lr)*264 + (kc*4 + lc)*8];
        s0 = __builtin_amdgcn_mfma_f32_16x16x32_bf16(qf[kc], k0, s0, 0,0,0);
        s1 = __builtin_amdgcn_mfma_f32_16x16x32_bf16(qf[kc], k1, s1, 0,0,0);
      }
      float sv0[4], sv1[4], alpha[4];
      #pragma unroll
      for(int r=0;r<4;r++){
        int gr = wrow0 + lc*4 + r;
        float x0 = s0[r]*0.0625f; int gj0 = j0 + lr;
        float x1 = s1[r]*0.0625f; int gj1 = j0 + 16 + lr;
        if(gj0 > gr || x0 == 0.0f) x0 = -INFINITY;
        if(gj1 > gr || x1 == 0.0f) x1 = -INFINITY;
        sv0[r]=x0; sv1[r]=x1;
      }
      #pragma unroll
      for(int r=0;r<4;r++){
        float mx = fmaxf(sv0[r], sv1[r]);
        #pragma unroll
        for(int dd=1; dd<16; dd<<=1) mx = fmaxf(mx, __shfl_xor(mx, dd));
        float mn = fmaxf(m[r], mx);
        alpha[r] = (m[r] == mn) ? 1.0f : __expf(m[r] - mn);
        float p0 = (sv0[r] == -INFINITY) ? 0.f : __expf(sv0[r] - mn);
        float p1 = (sv1[r] == -INFINITY) ? 0.f : __expf(sv1[r] - mn);
        pbuf[w][lc*4+r][lr]      = f2bf(p0);
        pbuf[w][lc*4+r][16 + lr] = f2bf(p1);
        float ps = p0 + p1;
        #pragma unroll
        for(int dd=1; dd<16; dd<<=1) ps += __shfl_xor(ps, dd);
        lsum[r] = lsum[r]*alpha[r] + ps;
        m[r] = mn;
      }
      #pragma unroll
      for(int n=0;n<16;n++){
        #pragma unroll
        for(int r=0;r<4;r++) o[n][r] *= alpha[r];
      }
    }
    __syncthreads();
    if(active){
      bf16x8 pa = *(const bf16x8*)&pbuf[w][lr][lc*8];
      #pragma unroll
      for(int n=0;n<16;n++){
        bf16x8 vf = *(const bf16x8*)&vtbuf[(n*16 + lr)*40 + lc*8];
        o[n] = __builtin_amdgcn_mfma_f32_16x16x32_bf16(pa, vf, o[n], 0,0,0);
      }
    }
    __syncthreads();
  }

  // epilogue: unnormalized partial + (m, l)
  float* obase = (s ? out1 : out0) + ((size_t)b*T + wrow0)*D;
  #pragma unroll
  for(int r=0;r<4;r++){
    #pragma unroll
    for(int n=0;n<16;n++){
      obase[(size_t)(lc*4 + r)*D + n*16 + lr] = o[n][r];
    }
  }
  if(lr == 0){
    float* mlb = ml + ((size_t)s*4*T + (size_t)b*T + wrow0)*2;
    #pragma unroll
    for(int r=0;r<4;r++){
      mlb[(lc*4+r)*2]     = m[r];
      mlb[(lc*4+r)*2 + 1] = lsum[r];
    }
  }
}

// ---------------- combine: out = (a1*o0 + a2*o1) / (a1*l1 + a2*l2) ----------------
__global__ __launch_bounds__(256) void combine_kernel(
    const float* __restrict__ part1, const float* __restrict__ ml,
    float* __restrict__ out){
  size_t idx = (size_t)blockIdx.x*256 + threadIdx.x;  // group of 4 floats
  size_t e = idx*4;
  size_t row = e >> 8;  // b*T + t
  float m1 = ml[row*2],            l1 = ml[row*2 + 1];
  float m2 = ml[(4*(size_t)T + row)*2], l2 = ml[(4*(size_t)T + row)*2 + 1];
  float mm = fmaxf(m1, m2);
  float a1 = __expf(m1 - mm);
  float a2 = __expf(m2 - mm);
  float inv = 1.0f / (a1*l1 + a2*l2);
  f32x4 v0 = *(const f32x4*)&out[e];
  f32x4 v1 = *(const f32x4*)&part1[e];
  f32x4 r;
  #pragma unroll
  for(int x=0;x<4;x++) r[x] = (a1*v0[x] + a2*v1[x]) * inv;
  *(f32x4*)&out[e] = r;
}

extern "C" void kernel_launch(void* const* d_in, const int* in_sizes, int n_in,
                              void* d_out, int out_size, void* d_ws, size_t ws_size,
                              hipStream_t stream){
  (void)in_sizes; (void)n_in; (void)out_size; (void)ws_size;
  const float* query = (const float*)d_in[0];
  const float* value = (const float*)d_in[1];
  const float* q_vec = (const float*)d_in[2];
  const float* k_vec = (const float*)d_in[3];
  const float* v_vec = (const float*)d_in[4];
  const float* Wq    = (const float*)d_in[5];
  const float* bq    = (const float*)d_in[6];
  const float* Ws    = (const float*)d_in[7];
  const float* bs    = (const float*)d_in[8];
  const float* Wt    = (const float*)d_in[9];
  const float* bt    = (const float*)d_in[10];
  char* ws = (char*)d_ws;
  unsigned short* q_g  = (unsigned short*)(ws);             //  8,388,608 B
  unsigned short* k_g  = (unsigned short*)(ws + 8388608);   //  8,912,896 B
  unsigned short* vt_g = (unsigned short*)(ws + 17301504);  // 10,485,760 B
  float* gates         = (float*)(ws + 27787264);           //      4,096 B
  float* part1         = (float*)(ws + 27791360);           // 16,777,216 B
  float* ml            = (float*)(ws + 44568576);           //    262,144 B
  float* out = (float*)d_out;                               // total ws: 44,830,720 B

  hipLaunchKernelGGL(prep0_kernel, dim3(1),   dim3(256), 0, stream,
                     q_vec, k_vec, v_vec, Ws, bs, Wt, bt, gates);
  hipLaunchKernelGGL(proj_kernel,  dim3(256), dim3(256), 0, stream,
                     query, Wq, bq, gates, q_g);
  hipLaunchKernelGGL(prep1_kernel, dim3(512), dim3(256), 0, stream,
                     value, gates, k_g, vt_g);
  hipLaunchKernelGGL(flash_kernel, dim3(512), dim3(256), 0, stream,
                     q_g, k_g, vt_g, out, part1, ml);
  hipLaunchKernelGGL(combine_kernel, dim3((4*T*D/4)/256), dim3(256), 0, stream,
                     part1, ml, out);
}